// Round 1
// baseline (861.476 us; speedup 1.0000x reference)
//
#include <hip/hip_runtime.h>
#include <hip/hip_bf16.h>

// Problem constants
#define Bb 8
#define Nn 4096
#define Mm 256
#define Dd 1024
#define Hh 16
#define HDd 64
#define Ss 4352   // N + M
#define INNERd 1024

typedef __attribute__((ext_vector_type(4))) float f32x4;
typedef __attribute__((ext_vector_type(8))) short short8;
typedef __attribute__((ext_vector_type(4))) int int4v;

__device__ __forceinline__ float bf2f(short u) {
  union { unsigned int i; float f; } c;
  c.i = ((unsigned int)(unsigned short)u) << 16;
  return c.f;
}
__device__ __forceinline__ short f2bf(float f) {
  union { float f; unsigned int i; } c; c.f = f;
  unsigned int x = c.i;
  x += 0x7fff + ((x >> 16) & 1);   // RNE
  return (short)(x >> 16);
}

// ---------------- LayerNorm (row of 1024 f32) -> bf16 ----------------
__global__ void ln_bf16_kernel(const float* __restrict__ src,
                               const float* __restrict__ w,
                               const float* __restrict__ bvec,
                               short* __restrict__ dst) {
  int row = blockIdx.x;
  const float4* x4 = (const float4*)(src + (size_t)row * Dd);
  int t = threadIdx.x;                       // 256 threads, 4 f32 each
  float4 v = x4[t];
  float s  = v.x + v.y + v.z + v.w;
  float ss = v.x*v.x + v.y*v.y + v.z*v.z + v.w*v.w;
#pragma unroll
  for (int o = 1; o < 64; o <<= 1) {
    s  += __shfl_xor(s,  o, 64);
    ss += __shfl_xor(ss, o, 64);
  }
  __shared__ float red[8];
  int wv = t >> 6;
  if ((t & 63) == 0) { red[wv] = s; red[4 + wv] = ss; }
  __syncthreads();
  float tot  = red[0] + red[1] + red[2] + red[3];
  float tot2 = red[4] + red[5] + red[6] + red[7];
  float mean = tot * (1.0f / Dd);
  float var  = tot2 * (1.0f / Dd) - mean * mean;
  float inv  = rsqrtf(var + 1e-5f);
  float4 wv4 = ((const float4*)w)[t];
  float4 bv4 = ((const float4*)bvec)[t];
  short4 o4;
  o4.x = f2bf((v.x - mean) * inv * wv4.x + bv4.x);
  o4.y = f2bf((v.y - mean) * inv * wv4.y + bv4.y);
  o4.z = f2bf((v.z - mean) * inv * wv4.z + bv4.z);
  o4.w = f2bf((v.w - mean) * inv * wv4.w + bv4.w);
  *(short4*)(dst + (size_t)row * Dd + t * 4) = o4;
}

// ------------- weight convert f32[K][N] -> bf16 transposed [N][K] -------------
__global__ void wconv_kernel(const float* __restrict__ src, short* __restrict__ dst,
                             int K, int Ncol) {
  __shared__ float tile[32][33];
  int bx = blockIdx.x, by = blockIdx.y;
  int tx = threadIdx.x, ty = threadIdx.y;
#pragma unroll
  for (int i = 0; i < 32; i += 8)
    tile[ty + i][tx] = src[(size_t)(by * 32 + ty + i) * Ncol + bx * 32 + tx];
  __syncthreads();
#pragma unroll
  for (int i = 0; i < 32; i += 8)
    dst[(size_t)(bx * 32 + ty + i) * K + by * 32 + tx] = f2bf(tile[tx][ty + i]);
}

// ---------------- GEMM: C[M][N] = A[M][K](bf16) * Bt[N][K](bf16)^T ----------------
// 128x128 tile, 4 waves (each 64x64), BK=32, 16x16x32 MFMA.
// LDS XOR-swizzle: 16B chunk c stored at physical chunk c^(row&3) (both sides).
// MODE 0: C fp32 row-major (stride Ncols)
// MODE 1: q scatter: bf16 * 0.125 -> [B,H,M,HD]
// MODE 2: kv_x scatter: col<1024 -> k_buf (C), else v_buf (C2), s=n
// MODE 3: kv_l scatter: s = N + m
template<int MODE>
__global__ void gemm_bt_kernel(const short* __restrict__ A, const short* __restrict__ Bt,
                               void* __restrict__ C, short* __restrict__ C2,
                               int Ncols, int K) {
  __shared__ __align__(16) short Asm[128 * 32];
  __shared__ __align__(16) short Bsm[128 * 32];
  int t = threadIdx.x;
  int wave = t >> 6, lane = t & 63;
  int wm = (wave >> 1) * 64, wn = (wave & 1) * 64;
  int brow = blockIdx.y * 128, bcol = blockIdx.x * 128;
  int lr = lane & 15, lg = lane >> 4;
  f32x4 acc[4][4] = {};
  for (int kt = 0; kt < K; kt += 32) {
    __syncthreads();
#pragma unroll
    for (int u = 0; u < 2; u++) {
      int cid = t + u * 256;                 // 512 16B-chunks per tile
      int r = cid >> 2, c = cid & 3;
      int cl = c ^ (r & 3);
      *(int4v*)(Asm + r * 32 + c * 8) =
          *(const int4v*)(A + (size_t)(brow + r) * K + kt + cl * 8);
      *(int4v*)(Bsm + r * 32 + c * 8) =
          *(const int4v*)(Bt + (size_t)(bcol + r) * K + kt + cl * 8);
    }
    __syncthreads();
    short8 a[4], b[4];
#pragma unroll
    for (int i = 0; i < 4; i++) {
      int ra = wm + i * 16 + lr;
      a[i] = *(const short8*)(Asm + ra * 32 + (lg ^ (ra & 3)) * 8);
      int rb = wn + i * 16 + lr;
      b[i] = *(const short8*)(Bsm + rb * 32 + (lg ^ (rb & 3)) * 8);
    }
#pragma unroll
    for (int mi = 0; mi < 4; mi++)
#pragma unroll
      for (int ni = 0; ni < 4; ni++)
        acc[mi][ni] = __builtin_amdgcn_mfma_f32_16x16x32_bf16(a[mi], b[ni], acc[mi][ni], 0, 0, 0);
  }
#pragma unroll
  for (int mi = 0; mi < 4; mi++)
#pragma unroll
    for (int ni = 0; ni < 4; ni++)
#pragma unroll
      for (int r = 0; r < 4; r++) {
        int row = brow + wm + mi * 16 + lg * 4 + r;
        int col = bcol + wn + ni * 16 + lr;
        float v = acc[mi][ni][r];
        if (MODE == 0) {
          ((float*)C)[(size_t)row * Ncols + col] = v;
        } else if (MODE == 1) {
          int bb = row >> 8, m = row & 255;
          int h = col >> 6, d = col & 63;
          ((short*)C)[(((size_t)(bb * Hh + h)) * Mm + m) * HDd + d] = f2bf(v * 0.125f);
        } else if (MODE == 2) {
          int bb = row >> 12, n = row & 4095;
          int cc = col & 1023;
          int h = cc >> 6, d = cc & 63;
          short* dstp = (col < 1024) ? (short*)C : C2;
          dstp[(((size_t)(bb * Hh + h)) * Ss + n) * HDd + d] = f2bf(v);
        } else {
          int bb = row >> 8, m = row & 255;
          int cc = col & 1023;
          int h = cc >> 6, d = cc & 63;
          short* dstp = (col < 1024) ? (short*)C : C2;
          dstp[(((size_t)(bb * Hh + h)) * Ss + (Nn + m)) * HDd + d] = f2bf(v);
        }
      }
}

// ---------------- 2D RoPE in place on k_buf rows s<4096, dims d<32 ----------------
__global__ void rope_kernel(short* __restrict__ kb) {
  int t = threadIdx.x;
  int d = t & 31;
  int rl = blockIdx.x * 8 + (t >> 5);        // row over B*H*N
  int b = rl >> 16;
  int h = (rl >> 12) & 15;
  int s = rl & 4095;
  size_t addr = (((size_t)(b * Hh + h)) * Ss + s) * HDd + d;
  float v = bf2f(kb[addr]);
  float p = __shfl_xor(v, 16, 32);           // partner d ^ 16
  int hp = s >> 6, wp = s & 63;
  float pos = (d & 8) ? (float)wp : (float)hp;
  int f = d & 7;
  float invf = exp2f(-1.6609640474436813f * (float)f);  // base^{-f/8}
  float ang = pos * invf;
  float cs = cosf(ang), sn = sinf(ang);
  float outv = (d < 16) ? (v * cs - p * sn) : (v * cs + p * sn);
  kb[addr] = f2bf(outv);
}

// ---------------- flash attention: blocks = (b,h,half), 4 waves x 32 q-rows ----------------
__global__ void attn_kernel(const short* __restrict__ qb,
                            const short* __restrict__ kb,
                            const short* __restrict__ vb,
                            short* __restrict__ ob) {
  __shared__ __align__(16) short Ksm[64 * 64];       // [key][d], chunk^=(key&7)
  __shared__ __align__(16) short Vsm[64 * 64];       // [d][key], chunk^=(d&7)
  __shared__ __align__(16) short Psm[4][32 * 64];    // per-wave P, chunk^=(row&7)
  int blk = blockIdx.x;
  int hf = blk & 1, bh = blk >> 1;
  int t = threadIdx.x, wave = t >> 6, lane = t & 63;
  int lr = lane & 15, lg = lane >> 4;
  int q0 = hf * 128 + wave * 32;
  const short* qptr = qb + (size_t)bh * Mm * HDd;
  short8 qf[2][2];
#pragma unroll
  for (int mi = 0; mi < 2; mi++)
#pragma unroll
    for (int ks = 0; ks < 2; ks++)
      qf[mi][ks] = *(const short8*)(qptr + (size_t)(q0 + mi * 16 + lr) * HDd + ks * 32 + lg * 8);
  f32x4 accO[2][4] = {};
  float mrow[2][4], srow[2][4];
#pragma unroll
  for (int mi = 0; mi < 2; mi++)
#pragma unroll
    for (int r = 0; r < 4; r++) { mrow[mi][r] = -1e30f; srow[mi][r] = 0.0f; }
  const short* kbase = kb + (size_t)bh * Ss * HDd;
  const short* vbase = vb + (size_t)bh * Ss * HDd;
  short* P = &Psm[wave][0];
  for (int kt = 0; kt < Ss; kt += 64) {
    __syncthreads();
#pragma unroll
    for (int u = 0; u < 2; u++) {
      int cid = t + u * 256;
      int r = cid >> 3, c = cid & 7;
      int cl = c ^ (r & 7);
      *(int4v*)(Ksm + r * 64 + c * 8) =
          *(const int4v*)(kbase + (size_t)(kt + r) * HDd + cl * 8);
      short8 vv = *(const short8*)(vbase + (size_t)(kt + r) * HDd + c * 8);
#pragma unroll
      for (int e = 0; e < 8; e++) {
        int d = c * 8 + e;
        Vsm[d * 64 + (((r >> 3) ^ (d & 7)) * 8) + (r & 7)] = vv[e];
      }
    }
    __syncthreads();
    // S = Q @ K^T
    f32x4 accS[2][4] = {};
#pragma unroll
    for (int ks = 0; ks < 2; ks++) {
      short8 bk[4];
#pragma unroll
      for (int ji = 0; ji < 4; ji++) {
        int j = ji * 16 + lr;
        int cd = ks * 4 + lg;
        bk[ji] = *(const short8*)(Ksm + j * 64 + ((cd ^ (j & 7)) * 8));
      }
#pragma unroll
      for (int mi = 0; mi < 2; mi++)
#pragma unroll
        for (int ji = 0; ji < 4; ji++)
          accS[mi][ji] = __builtin_amdgcn_mfma_f32_16x16x32_bf16(qf[mi][ks], bk[ji], accS[mi][ji], 0, 0, 0);
    }
    // online softmax (fp32, 16-lane reductions)
#pragma unroll
    for (int mi = 0; mi < 2; mi++)
#pragma unroll
      for (int r = 0; r < 4; r++) {
        float mx = fmaxf(fmaxf(accS[mi][0][r], accS[mi][1][r]),
                         fmaxf(accS[mi][2][r], accS[mi][3][r]));
#pragma unroll
        for (int o = 1; o < 16; o <<= 1) mx = fmaxf(mx, __shfl_xor(mx, o, 64));
        float mnew = fmaxf(mrow[mi][r], mx);
        float corr = __expf(mrow[mi][r] - mnew);
        mrow[mi][r] = mnew;
        float rs = 0.0f;
#pragma unroll
        for (int ji = 0; ji < 4; ji++) {
          float pv = __expf(accS[mi][ji][r] - mnew);
          accS[mi][ji][r] = pv;
          rs += pv;
        }
#pragma unroll
        for (int o = 1; o < 16; o <<= 1) rs += __shfl_xor(rs, o, 64);
        srow[mi][r] = srow[mi][r] * corr + rs;
#pragma unroll
        for (int di = 0; di < 4; di++) accO[mi][di][r] *= corr;
      }
    // P -> LDS (wave-private, swizzled), bf16
#pragma unroll
    for (int mi = 0; mi < 2; mi++)
#pragma unroll
      for (int ji = 0; ji < 4; ji++)
#pragma unroll
        for (int r = 0; r < 4; r++) {
          int row = mi * 16 + lg * 4 + r;
          int col = ji * 16 + lr;
          P[row * 64 + (((col >> 3) ^ (row & 7)) * 8) + (col & 7)] = f2bf(accS[mi][ji][r]);
        }
    // O += P @ V
#pragma unroll
    for (int ks = 0; ks < 2; ks++) {
      short8 pa[2], bvv[4];
#pragma unroll
      for (int mi = 0; mi < 2; mi++) {
        int row = mi * 16 + lr;
        int ck = ks * 4 + lg;
        pa[mi] = *(const short8*)(P + row * 64 + ((ck ^ (row & 7)) * 8));
      }
#pragma unroll
      for (int di = 0; di < 4; di++) {
        int d = di * 16 + lr;
        int ck = ks * 4 + lg;
        bvv[di] = *(const short8*)(Vsm + d * 64 + ((ck ^ (d & 7)) * 8));
      }
#pragma unroll
      for (int mi = 0; mi < 2; mi++)
#pragma unroll
        for (int di = 0; di < 4; di++)
          accO[mi][di] = __builtin_amdgcn_mfma_f32_16x16x32_bf16(pa[mi], bvv[di], accO[mi][di], 0, 0, 0);
    }
  }
  int bb = bh >> 4, h = bh & 15;
#pragma unroll
  for (int mi = 0; mi < 2; mi++)
#pragma unroll
    for (int di = 0; di < 4; di++)
#pragma unroll
      for (int r = 0; r < 4; r++) {
        int qm = q0 + mi * 16 + lg * 4 + r;
        int d = di * 16 + lr;
        float v = accO[mi][di][r] / srow[mi][r];
        ob[((size_t)(bb * Mm + qm)) * INNERd + h * HDd + d] = f2bf(v);
      }
}

extern "C" void kernel_launch(void* const* d_in, const int* in_sizes, int n_in,
                              void* d_out, int out_size, void* d_ws, size_t ws_size,
                              hipStream_t stream) {
  const float* x    = (const float*)d_in[0];
  const float* lat  = (const float*)d_in[1];
  const float* lnxw = (const float*)d_in[2];
  const float* lnxb = (const float*)d_in[3];
  const float* lnlw = (const float*)d_in[4];
  const float* lnlb = (const float*)d_in[5];
  const float* Wq   = (const float*)d_in[6];
  const float* Wkv  = (const float*)d_in[7];
  const float* Wo   = (const float*)d_in[8];
  char* w = (char*)d_ws;
  const size_t MB = 1048576;
  short* Wqt  = (short*)(w + 0 * MB);      // 2 MB
  short* Wkvt = (short*)(w + 2 * MB);      // 4 MB
  short* Wot  = (short*)(w + 6 * MB);      // 2 MB
  short* xn   = (short*)(w + 8 * MB);      // 64 MB
  short* lnr  = (short*)(w + 72 * MB);     // 4 MB
  short* qbuf = (short*)(w + 76 * MB);     // 4 MB
  short* kbuf = (short*)(w + 80 * MB);     // 68 MB
  short* vbuf = (short*)(w + 148 * MB);    // 68 MB
  short* aout = (short*)(w + 216 * MB);    // 4 MB

  ln_bf16_kernel<<<dim3(Bb * Nn), dim3(256), 0, stream>>>(x, lnxw, lnxb, xn);
  ln_bf16_kernel<<<dim3(Bb * Mm), dim3(256), 0, stream>>>(lat, lnlw, lnlb, lnr);
  wconv_kernel<<<dim3(32, 32), dim3(32, 8), 0, stream>>>(Wq, Wqt, 1024, 1024);
  wconv_kernel<<<dim3(64, 32), dim3(32, 8), 0, stream>>>(Wkv, Wkvt, 1024, 2048);
  wconv_kernel<<<dim3(32, 32), dim3(32, 8), 0, stream>>>(Wo, Wot, 1024, 1024);
  // kv_x = xn @ Wkv -> scatter k/v
  gemm_bt_kernel<2><<<dim3(16, 256), dim3(256), 0, stream>>>(xn, Wkvt, (void*)kbuf, vbuf, 2048, 1024);
  // q = lnr @ Wq (scaled 0.125)
  gemm_bt_kernel<1><<<dim3(8, 16), dim3(256), 0, stream>>>(lnr, Wqt, (void*)qbuf, (short*)nullptr, 1024, 1024);
  // kv_l = lnr @ Wkv -> scatter at s = N + m
  gemm_bt_kernel<3><<<dim3(16, 16), dim3(256), 0, stream>>>(lnr, Wkvt, (void*)kbuf, vbuf, 2048, 1024);
  rope_kernel<<<dim3(65536), dim3(256), 0, stream>>>(kbuf);
  attn_kernel<<<dim3(256), dim3(256), 0, stream>>>(qbuf, kbuf, vbuf, aout);
  // out = aout @ Wo (fp32)
  gemm_bt_kernel<0><<<dim3(8, 16), dim3(256), 0, stream>>>(aout, Wot, d_out, (short*)nullptr, 1024, 1024);
}

// Round 2
// 424.250 us; speedup vs baseline: 2.0306x; 2.0306x over previous
//
#include <hip/hip_runtime.h>
#include <hip/hip_bf16.h>

// Problem constants
#define Bb 8
#define Nn 4096
#define Mm 256
#define Dd 1024
#define Hh 16
#define HDd 64
#define Ss 4352   // N + M
#define INNERd 1024
#define SPLIT 8

typedef __attribute__((ext_vector_type(4))) float f32x4;
typedef __attribute__((ext_vector_type(8))) short short8;
typedef __attribute__((ext_vector_type(4))) int int4v;

__device__ __forceinline__ float bf2f(short u) {
  union { unsigned int i; float f; } c;
  c.i = ((unsigned int)(unsigned short)u) << 16;
  return c.f;
}
__device__ __forceinline__ short f2bf(float f) {
  union { float f; unsigned int i; } c; c.f = f;
  unsigned int x = c.i;
  x += 0x7fff + ((x >> 16) & 1);   // RNE
  return (short)(x >> 16);
}
__device__ __forceinline__ void gload16(const short* g, short* l) {
  __builtin_amdgcn_global_load_lds(
      (const __attribute__((address_space(1))) void*)g,
      (__attribute__((address_space(3))) void*)l, 16, 0, 0);
}

// ---------------- LayerNorm (row of 1024 f32) -> bf16 ----------------
__global__ void ln_bf16_kernel(const float* __restrict__ src,
                               const float* __restrict__ w,
                               const float* __restrict__ bvec,
                               short* __restrict__ dst) {
  int row = blockIdx.x;
  const float4* x4 = (const float4*)(src + (size_t)row * Dd);
  int t = threadIdx.x;                       // 256 threads, 4 f32 each
  float4 v = x4[t];
  float s  = v.x + v.y + v.z + v.w;
  float ss = v.x*v.x + v.y*v.y + v.z*v.z + v.w*v.w;
#pragma unroll
  for (int o = 1; o < 64; o <<= 1) {
    s  += __shfl_xor(s,  o, 64);
    ss += __shfl_xor(ss, o, 64);
  }
  __shared__ float red[8];
  int wv = t >> 6;
  if ((t & 63) == 0) { red[wv] = s; red[4 + wv] = ss; }
  __syncthreads();
  float tot  = red[0] + red[1] + red[2] + red[3];
  float tot2 = red[4] + red[5] + red[6] + red[7];
  float mean = tot * (1.0f / Dd);
  float var  = tot2 * (1.0f / Dd) - mean * mean;
  float inv  = rsqrtf(var + 1e-5f);
  float4 wv4 = ((const float4*)w)[t];
  float4 bv4 = ((const float4*)bvec)[t];
  short4 o4;
  o4.x = f2bf((v.x - mean) * inv * wv4.x + bv4.x);
  o4.y = f2bf((v.y - mean) * inv * wv4.y + bv4.y);
  o4.z = f2bf((v.z - mean) * inv * wv4.z + bv4.z);
  o4.w = f2bf((v.w - mean) * inv * wv4.w + bv4.w);
  *(short4*)(dst + (size_t)row * Dd + t * 4) = o4;
}

// ------------- weight convert f32[K][N] -> bf16 transposed [N][K] -------------
__global__ void wconv_kernel(const float* __restrict__ src, short* __restrict__ dst,
                             int K, int Ncol) {
  __shared__ float tile[32][33];
  int bx = blockIdx.x, by = blockIdx.y;
  int tx = threadIdx.x, ty = threadIdx.y;
#pragma unroll
  for (int i = 0; i < 32; i += 8)
    tile[ty + i][tx] = src[(size_t)(by * 32 + ty + i) * Ncol + bx * 32 + tx];
  __syncthreads();
#pragma unroll
  for (int i = 0; i < 32; i += 8)
    dst[(size_t)(bx * 32 + ty + i) * K + by * 32 + tx] = f2bf(tile[tx][ty + i]);
}

// ---------------- GEMM: C[M][N] = A[M][K](bf16) * Bt[N][K](bf16)^T ----------------
// 128x128 tile, 4 waves (each 64x64), BK=32, 16x16x32 MFMA.
// Staging via global_load_lds width-16: LINEAR LDS dest + pre-swizzled global src;
// read side applies chunk ^= (row&3). (both-sides-or-neither rule)
// MODE 0: C fp32 row-major (stride Ncols)
// MODE 1: q scatter: bf16 * 0.125 -> [B,H,M,HD]
// MODE 2: kv_x scatter + fused 2D-RoPE on k dims d<32: col<1024 -> k_buf, else v_buf
// MODE 3: kv_l scatter: s = N + m (no rope)
template<int MODE>
__global__ void gemm_bt_kernel(const short* __restrict__ A, const short* __restrict__ Bt,
                               void* __restrict__ C, short* __restrict__ C2,
                               int Ncols, int K) {
  __shared__ __align__(16) short Asm[128 * 32];
  __shared__ __align__(16) short Bsm[128 * 32];
  __shared__ float ctab[1024];               // cos[512], sin[512] (MODE 2)
  int t = threadIdx.x;
  int wave = t >> 6, lane = t & 63;
  int wm = (wave >> 1) * 64, wn = (wave & 1) * 64;
  int brow = blockIdx.y * 128, bcol = blockIdx.x * 128;
  int lr = lane & 15, lg = lane >> 4;
  if (MODE == 2) {
#pragma unroll
    for (int i = t; i < 512; i += 256) {
      int pos = i >> 3, f = i & 7;
      float ang = (float)pos * exp2f(-1.6609640474436813f * (float)f);
      ctab[i] = cosf(ang);
      ctab[512 + i] = sinf(ang);
    }
  }
  f32x4 acc[4][4] = {};
  for (int kt = 0; kt < K; kt += 32) {
    __syncthreads();
#pragma unroll
    for (int u = 0; u < 2; u++) {
      int cid = t + u * 256;                 // 512 16B-chunks per tile
      int r = cid >> 2, c = cid & 3;
      int cl = c ^ (r & 3);                  // pre-swizzled global source
      gload16(A + (size_t)(brow + r) * K + kt + cl * 8, Asm + cid * 8);
      gload16(Bt + (size_t)(bcol + r) * K + kt + cl * 8, Bsm + cid * 8);
    }
    __syncthreads();
    short8 a[4], b[4];
#pragma unroll
    for (int i = 0; i < 4; i++) {
      int ra = wm + i * 16 + lr;
      a[i] = *(const short8*)(Asm + ra * 32 + (lg ^ (ra & 3)) * 8);
      int rb = wn + i * 16 + lr;
      b[i] = *(const short8*)(Bsm + rb * 32 + (lg ^ (rb & 3)) * 8);
    }
#pragma unroll
    for (int mi = 0; mi < 4; mi++)
#pragma unroll
      for (int ni = 0; ni < 4; ni++)
        acc[mi][ni] = __builtin_amdgcn_mfma_f32_16x16x32_bf16(a[mi], b[ni], acc[mi][ni], 0, 0, 0);
  }
  bool kreg = (bcol + wn) < 1024;            // whole 64-col wave block in k-region
#pragma unroll
  for (int mi = 0; mi < 4; mi++)
#pragma unroll
    for (int r = 0; r < 4; r++) {
      int row = brow + wm + mi * 16 + lg * 4 + r;
      float v[4];
#pragma unroll
      for (int ni = 0; ni < 4; ni++) v[ni] = acc[mi][ni][r];
      if (MODE == 0) {
#pragma unroll
        for (int ni = 0; ni < 4; ni++)
          ((float*)C)[(size_t)row * Ncols + bcol + wn + ni * 16 + lr] = v[ni];
      } else if (MODE == 1) {
        int bb = row >> 8, m = row & 255;
#pragma unroll
        for (int ni = 0; ni < 4; ni++) {
          int col = wn + ni * 16 + lr;       // bcol==0 block-local? no: full col below
          int fc = bcol + col;
          int h = fc >> 6, d = fc & 63;
          ((short*)C)[(((size_t)(bb * Hh + h)) * Mm + m) * HDd + d] = f2bf(v[ni] * 0.125f);
        }
      } else if (MODE == 2) {
        int bb = row >> 12, n = row & 4095;
        if (kreg) {                           // fused 2D RoPE on d<32 (ni 0,1)
          int pos = (lr & 8) ? (n & 63) : (n >> 6);
          float cs = ctab[pos * 8 + (lr & 7)];
          float sn = ctab[512 + pos * 8 + (lr & 7)];
          float v0 = v[0], v1 = v[1];
          v[0] = v0 * cs - v1 * sn;
          v[1] = v1 * cs + v0 * sn;
        }
        short* dstp = kreg ? (short*)C : C2;
#pragma unroll
        for (int ni = 0; ni < 4; ni++) {
          int cc = (bcol + wn + ni * 16 + lr) & 1023;
          int h = cc >> 6, d = cc & 63;
          dstp[(((size_t)(bb * Hh + h)) * Ss + n) * HDd + d] = f2bf(v[ni]);
        }
      } else {
        int bb = row >> 8, m = row & 255;
        short* dstp = kreg ? (short*)C : C2;
#pragma unroll
        for (int ni = 0; ni < 4; ni++) {
          int cc = (bcol + wn + ni * 16 + lr) & 1023;
          int h = cc >> 6, d = cc & 63;
          dstp[(((size_t)(bb * Hh + h)) * Ss + (Nn + m)) * HDd + d] = f2bf(v[ni]);
        }
      }
    }
}

// ---------------- flash attention, KV-split: blocks = (b,h)*SPLIT, 8 waves x 32 q-rows ----
__global__ __launch_bounds__(512) void attn_kernel(const short* __restrict__ qb,
                            const short* __restrict__ kb,
                            const short* __restrict__ vb,
                            float* __restrict__ pO,
                            float* __restrict__ pMS) {
  __shared__ __align__(16) short Ksm[64 * 64];       // [key][d], chunk^=(key&7)
  __shared__ __align__(16) short Vsm[64 * 64];       // [d][key], chunk^=(d&7)
  __shared__ __align__(16) short Psm[8][32 * 64];    // per-wave P, chunk^=(row&7)
  int blk = blockIdx.x;
  int sp = blk & (SPLIT - 1), bh = blk >> 3;
  int t = threadIdx.x, wave = t >> 6, lane = t & 63;
  int lr = lane & 15, lg = lane >> 4;
  int q0 = wave * 32;
  const short* qptr = qb + (size_t)bh * Mm * HDd;
  short8 qf[2][2];
#pragma unroll
  for (int mi = 0; mi < 2; mi++)
#pragma unroll
    for (int ks = 0; ks < 2; ks++)
      qf[mi][ks] = *(const short8*)(qptr + (size_t)(q0 + mi * 16 + lr) * HDd + ks * 32 + lg * 8);
  f32x4 accO[2][4] = {};
  float mrow[2][4], srow[2][4];
#pragma unroll
  for (int mi = 0; mi < 2; mi++)
#pragma unroll
    for (int r = 0; r < 4; r++) { mrow[mi][r] = -1e30f; srow[mi][r] = 0.0f; }
  const short* kbase = kb + (size_t)bh * Ss * HDd;
  const short* vbase = vb + (size_t)bh * Ss * HDd;
  short* P = &Psm[wave][0];
  int tile0 = (sp * 68) >> 3, tile1 = ((sp + 1) * 68) >> 3;
  for (int tt = tile0; tt < tile1; tt++) {
    int kt = tt * 64;
    __syncthreads();
    {
      int r = t >> 3, c = t & 7;             // 512 threads, one 16B chunk each
      int cl = c ^ (r & 7);
      gload16(kbase + (size_t)(kt + r) * HDd + cl * 8, Ksm + t * 8);
      short8 vv = *(const short8*)(vbase + (size_t)(kt + r) * HDd + c * 8);
#pragma unroll
      for (int e = 0; e < 8; e++) {
        int d = c * 8 + e;
        Vsm[d * 64 + (((r >> 3) ^ (d & 7)) * 8) + (r & 7)] = vv[e];
      }
    }
    __syncthreads();
    // S = Q @ K^T
    f32x4 accS[2][4] = {};
#pragma unroll
    for (int ks = 0; ks < 2; ks++) {
      short8 bk[4];
#pragma unroll
      for (int ji = 0; ji < 4; ji++) {
        int j = ji * 16 + lr;
        int cd = ks * 4 + lg;
        bk[ji] = *(const short8*)(Ksm + j * 64 + ((cd ^ (j & 7)) * 8));
      }
#pragma unroll
      for (int mi = 0; mi < 2; mi++)
#pragma unroll
        for (int ji = 0; ji < 4; ji++)
          accS[mi][ji] = __builtin_amdgcn_mfma_f32_16x16x32_bf16(qf[mi][ks], bk[ji], accS[mi][ji], 0, 0, 0);
    }
    // online softmax (fp32, 16-lane reductions)
#pragma unroll
    for (int mi = 0; mi < 2; mi++)
#pragma unroll
      for (int r = 0; r < 4; r++) {
        float mx = fmaxf(fmaxf(accS[mi][0][r], accS[mi][1][r]),
                         fmaxf(accS[mi][2][r], accS[mi][3][r]));
#pragma unroll
        for (int o = 1; o < 16; o <<= 1) mx = fmaxf(mx, __shfl_xor(mx, o, 64));
        float mnew = fmaxf(mrow[mi][r], mx);
        float corr = __expf(mrow[mi][r] - mnew);
        mrow[mi][r] = mnew;
        float rs = 0.0f;
#pragma unroll
        for (int ji = 0; ji < 4; ji++) {
          float pv = __expf(accS[mi][ji][r] - mnew);
          accS[mi][ji][r] = pv;
          rs += pv;
        }
#pragma unroll
        for (int o = 1; o < 16; o <<= 1) rs += __shfl_xor(rs, o, 64);
        srow[mi][r] = srow[mi][r] * corr + rs;
#pragma unroll
        for (int di = 0; di < 4; di++) accO[mi][di][r] *= corr;
      }
    // P -> LDS (wave-private, swizzled), bf16
#pragma unroll
    for (int mi = 0; mi < 2; mi++)
#pragma unroll
      for (int ji = 0; ji < 4; ji++)
#pragma unroll
        for (int r = 0; r < 4; r++) {
          int row = mi * 16 + lg * 4 + r;
          int col = ji * 16 + lr;
          P[row * 64 + (((col >> 3) ^ (row & 7)) * 8) + (col & 7)] = f2bf(accS[mi][ji][r]);
        }
    // O += P @ V
#pragma unroll
    for (int ks = 0; ks < 2; ks++) {
      short8 pa[2], bvv[4];
#pragma unroll
      for (int mi = 0; mi < 2; mi++) {
        int row = mi * 16 + lr;
        int ck = ks * 4 + lg;
        pa[mi] = *(const short8*)(P + row * 64 + ((ck ^ (row & 7)) * 8));
      }
#pragma unroll
      for (int di = 0; di < 4; di++) {
        int d = di * 16 + lr;
        int ck = ks * 4 + lg;
        bvv[di] = *(const short8*)(Vsm + d * 64 + ((ck ^ (d & 7)) * 8));
      }
#pragma unroll
      for (int mi = 0; mi < 2; mi++)
#pragma unroll
        for (int di = 0; di < 4; di++)
          accO[mi][di] = __builtin_amdgcn_mfma_f32_16x16x32_bf16(pa[mi], bvv[di], accO[mi][di], 0, 0, 0);
    }
  }
  // write split partials (unnormalized O in fp32 + per-row m,s)
  size_t base = (size_t)blk * 256;
#pragma unroll
  for (int mi = 0; mi < 2; mi++)
#pragma unroll
    for (int r = 0; r < 4; r++) {
      int m = q0 + mi * 16 + lg * 4 + r;
      if (lr == 0) {
        pMS[(base + m) * 2]     = mrow[mi][r];
        pMS[(base + m) * 2 + 1] = srow[mi][r];
      }
#pragma unroll
      for (int di = 0; di < 4; di++)
        pO[(base + m) * 64 + di * 16 + lr] = accO[mi][di][r];
    }
}

// ---------------- combine the SPLIT partials ----------------
__global__ void attn_combine(const float* __restrict__ pO, const float* __restrict__ pMS,
                             short* __restrict__ ob) {
  int t = threadIdx.x;
  int row = blockIdx.x * 4 + (t >> 6);       // over B*H*M = 32768
  int bh = row >> 8, m = row & 255;
  int d = t & 63;
  float mv[SPLIT], sv[SPLIT];
  float mx = -1e30f;
#pragma unroll
  for (int s = 0; s < SPLIT; s++) {
    size_t rbase = ((size_t)(bh * SPLIT + s) * 256 + m);
    mv[s] = pMS[rbase * 2];
    sv[s] = pMS[rbase * 2 + 1];
    mx = fmaxf(mx, mv[s]);
  }
  float den = 0.0f, acc = 0.0f;
#pragma unroll
  for (int s = 0; s < SPLIT; s++) {
    float wgt = __expf(mv[s] - mx);
    den += wgt * sv[s];
    acc += wgt * pO[((size_t)(bh * SPLIT + s) * 256 + m) * 64 + d];
  }
  int b = bh >> 4, h = bh & 15;
  ob[((size_t)(b * Mm + m)) * INNERd + h * HDd + d] = f2bf(acc / den);
}

extern "C" void kernel_launch(void* const* d_in, const int* in_sizes, int n_in,
                              void* d_out, int out_size, void* d_ws, size_t ws_size,
                              hipStream_t stream) {
  const float* x    = (const float*)d_in[0];
  const float* lat  = (const float*)d_in[1];
  const float* lnxw = (const float*)d_in[2];
  const float* lnxb = (const float*)d_in[3];
  const float* lnlw = (const float*)d_in[4];
  const float* lnlb = (const float*)d_in[5];
  const float* Wq   = (const float*)d_in[6];
  const float* Wkv  = (const float*)d_in[7];
  const float* Wo   = (const float*)d_in[8];
  char* w = (char*)d_ws;
  const size_t MB = 1048576;
  short* Wqt  = (short*)(w + 0 * MB);      // 2 MB
  short* Wkvt = (short*)(w + 2 * MB);      // 4 MB
  short* Wot  = (short*)(w + 6 * MB);      // 2 MB
  short* xn   = (short*)(w + 8 * MB);      // 64 MB (reused as pO by attn)
  short* lnr  = (short*)(w + 72 * MB);     // 4 MB (reused as pMS by attn)
  short* qbuf = (short*)(w + 76 * MB);     // 4 MB
  short* kbuf = (short*)(w + 80 * MB);     // 68 MB
  short* vbuf = (short*)(w + 148 * MB);    // 68 MB
  short* aout = (short*)(w + 216 * MB);    // 4 MB
  float* pO   = (float*)(w + 8 * MB);      // 64 MB, aliases xn (dead by attn time)
  float* pMS  = (float*)(w + 72 * MB);     // 2 MB, aliases lnr (dead by attn time)

  ln_bf16_kernel<<<dim3(Bb * Nn), dim3(256), 0, stream>>>(x, lnxw, lnxb, xn);
  ln_bf16_kernel<<<dim3(Bb * Mm), dim3(256), 0, stream>>>(lat, lnlw, lnlb, lnr);
  wconv_kernel<<<dim3(32, 32), dim3(32, 8), 0, stream>>>(Wq, Wqt, 1024, 1024);
  wconv_kernel<<<dim3(64, 32), dim3(32, 8), 0, stream>>>(Wkv, Wkvt, 1024, 2048);
  wconv_kernel<<<dim3(32, 32), dim3(32, 8), 0, stream>>>(Wo, Wot, 1024, 1024);
  // kv_x = xn @ Wkv -> scatter k/v, fused RoPE on k d<32
  gemm_bt_kernel<2><<<dim3(16, 256), dim3(256), 0, stream>>>(xn, Wkvt, (void*)kbuf, vbuf, 2048, 1024);
  // q = lnr @ Wq (scaled 0.125)
  gemm_bt_kernel<1><<<dim3(8, 16), dim3(256), 0, stream>>>(lnr, Wqt, (void*)qbuf, (short*)nullptr, 1024, 1024);
  // kv_l = lnr @ Wkv -> scatter at s = N + m
  gemm_bt_kernel<3><<<dim3(16, 16), dim3(256), 0, stream>>>(lnr, Wkvt, (void*)kbuf, vbuf, 2048, 1024);
  // flash attention with KV-split 8 + combine
  attn_kernel<<<dim3(Bb * Hh * SPLIT), dim3(512), 0, stream>>>(qbuf, kbuf, vbuf, pO, pMS);
  attn_combine<<<dim3(Bb * Hh * Mm / 4), dim3(256), 0, stream>>>(pO, pMS, aout);
  // out = aout @ Wo (fp32)
  gemm_bt_kernel<0><<<dim3(8, 16), dim3(256), 0, stream>>>(aout, Wot, d_out, (short*)nullptr, 1024, 1024);
}